// Round 9
// baseline (304.737 us; speedup 1.0000x reference)
//
#include <hip/hip_runtime.h>
#include <hip/hip_cooperative_groups.h>
#include <cstdint>

namespace cg = cooperative_groups;

// Problem constants
#define BB 8
#define LL 2048
#define DD 768
#define SS 512
#define MAXW 32

constexpr int M = BB * SS;   // 4096 spans
constexpr int K = 2 * DD;    // 1536
constexpr int N = DD;        // 768

typedef __attribute__((ext_vector_type(8))) short short8;   // 8 bf16 = 4 VGPRs
typedef __attribute__((ext_vector_type(4))) float f32x4;

__device__ __forceinline__ unsigned short f2bf(float f) {
    union { float f; unsigned int u; } v; v.f = f;
    unsigned int r = v.u + 0x7fffu + ((v.u >> 16) & 1u);  // RNE
    return (unsigned short)(r >> 16);
}
__device__ __forceinline__ float bf2f(unsigned short u) {
    union { unsigned int u; float f; } v; v.u = ((unsigned int)u) << 16;
    return v.f;
}

// generic -> addrspace casts for global_load_lds
#define AS1(p) reinterpret_cast<const __attribute__((address_space(1))) void*>( \
                   reinterpret_cast<uintptr_t>(p))
#define AS3(p) reinterpret_cast<__attribute__((address_space(3))) void*>( \
                   reinterpret_cast<uintptr_t>(p))

constexpr int BM = 64, BN = 64, BK = 64;

// ---------------------------------------------------------------------------
// FUSED cooperative kernel, grid 1024 x 256 (4 blocks/CU co-resident).
//  Phase A: repr f32->bf16 (block bid&7 = batch -> XCD L2 pin) + W transpose.
//  Phase B: wave-per-span gather from L2-resident bf16 slice (3.07MB < 4MB).
//  Phase C: blocks [0,768): one 64^3 MFMA GEMM tile each, XCD-aligned so the
//           A-panel (written by the same XCD in phase B) is L2-dirty local.
// ---------------------------------------------------------------------------
__global__ __launch_bounds__(256, 4) void fused_kernel(
    const float* __restrict__ repr,            // (B,L,D) f32
    const int*   __restrict__ spans,           // (B,S,2) int
    const float* __restrict__ W,               // (K,N) f32
    const float* __restrict__ bias,            // (N) f32
    unsigned short* __restrict__ cat,          // ws: (M, 2D) bf16
    unsigned short* __restrict__ WT,           // ws: (N, K) bf16
    unsigned short* __restrict__ reprb,        // ws: (B,L,D) bf16
    float*       __restrict__ out)             // (M, N) f32
{
    __shared__ __align__(16) char shraw[32768];          // GEMM dbuf / tbuf alias
    unsigned short* AsmB = (unsigned short*)shraw;       // [2][BM*BK]
    unsigned short* BsmB = (unsigned short*)(shraw + 16384);
    float (*tbuf)[33] = (float(*)[33])shraw;

    const int bid = blockIdx.x;
    const int tid = threadIdx.x;
    cg::grid_group grid = cg::this_grid();

    // ================= Phase A: convert + W transpose =================
    {
        const int b = bid & 7, c = bid >> 3;             // 128 blocks/batch
        const float4* src = (const float4*)repr + (size_t)b * (LL * DD / 4) + (size_t)c * 3072;
        ushort4* dst = (ushort4*)reprb + (size_t)b * (LL * DD / 4) + (size_t)c * 3072;
        #pragma unroll
        for (int i = 0; i < 12; ++i) {
            const float4 v = src[i * 256 + tid];
            ushort4 o;
            o.x = f2bf(v.x); o.y = f2bf(v.y); o.z = f2bf(v.z); o.w = f2bf(v.w);
            dst[i * 256 + tid] = o;
        }
    }
    for (int tt = bid; tt < 1152; tt += 1024) {          // W: 24x48 tiles of 32x32
        const int n0 = (tt % 24) * 32, k0 = (tt / 24) * 32;
        const int tx = tid & 31, ty = tid >> 5;          // (32, 8)
        __syncthreads();
        #pragma unroll
        for (int j = 0; j < 4; ++j)
            tbuf[ty + 8 * j][tx] = W[(size_t)(k0 + ty + 8 * j) * N + n0 + tx];
        __syncthreads();
        #pragma unroll
        for (int j = 0; j < 4; ++j)
            WT[(size_t)(n0 + ty + 8 * j) * K + k0 + tx] = f2bf(tbuf[tx][ty + 8 * j]);
    }

    grid.sync();

    // ================= Phase B: wave-per-span bf16 gather =================
    {
        const int wave = tid >> 6, lane = tid & 63;
        const int b = bid & 7;
        const int span = (b << 9) | ((bid >> 3) << 2) | wave;   // 1 span/wave

        const bool is64 = ((spans[1] | spans[3] | spans[5] | spans[7]) == 0);
        int st, en;
        if (is64) { st = spans[4 * span];     en = spans[4 * span + 2]; }
        else      { st = spans[2 * span];     en = spans[2 * span + 1]; }
        const int cnt = en - st + 1;                     // 1..32, wave-uniform

        const ushort4* base = (const ushort4*)reprb + (size_t)b * (LL * DD / 4);

        float4 mx[3], sm[3];
        #pragma unroll
        for (int c = 0; c < 3; ++c) {
            mx[c] = make_float4(-3.0e38f, -3.0e38f, -3.0e38f, -3.0e38f);
            sm[c] = make_float4(0.f, 0.f, 0.f, 0.f);
        }

        #define BACC(c, u) {                                               \
            const float x0 = bf2f((u).x), x1 = bf2f((u).y);                \
            const float x2 = bf2f((u).z), x3 = bf2f((u).w);                \
            mx[c].x = fmaxf(mx[c].x, x0); mx[c].y = fmaxf(mx[c].y, x1);    \
            mx[c].z = fmaxf(mx[c].z, x2); mx[c].w = fmaxf(mx[c].w, x3);    \
            sm[c].x += x0; sm[c].y += x1; sm[c].z += x2; sm[c].w += x3; }

        int w = 0;
        if (cnt & 1) {                                   // odd count: peel one
            const ushort4* rp = base + (size_t)en * (DD / 4) + lane;
            const ushort4 a0 = rp[0], a1 = rp[64], a2 = rp[128];
            BACC(0, a0); BACC(1, a1); BACC(2, a2);
            w = 1;
        }
        for (; w < cnt; w += 2) {                        // 6 loads in flight
            const ushort4* r0 = base + (size_t)(en - w) * (DD / 4) + lane;
            const ushort4* r1 = r0 - (DD / 4);
            const ushort4 a0 = r0[0], a1 = r0[64], a2 = r0[128];
            const ushort4 b0 = r1[0], b1 = r1[64], b2 = r1[128];
            BACC(0, a0); BACC(1, a1); BACC(2, a2);
            BACC(0, b0); BACC(1, b1); BACC(2, b2);
        }
        #undef BACC

        const float inv = 1.0f / (float)cnt;
        unsigned short* crow = cat + (size_t)span * K;
        #pragma unroll
        for (int c = 0; c < 3; ++c) {
            const int d4 = c * 64 + lane;
            ushort4 omax, omean;
            omax.x  = f2bf(mx[c].x);       omax.y  = f2bf(mx[c].y);
            omax.z  = f2bf(mx[c].z);       omax.w  = f2bf(mx[c].w);
            omean.x = f2bf(sm[c].x * inv); omean.y = f2bf(sm[c].y * inv);
            omean.z = f2bf(sm[c].z * inv); omean.w = f2bf(sm[c].w * inv);
            *(ushort4*)(crow + d4 * 4)      = omax;
            *(ushort4*)(crow + DD + d4 * 4) = omean;
        }
    }

    grid.sync();

    // ================= Phase C: GEMM (768 active blocks) =================
    if (bid >= 768) return;
    {
        // XCD-aligned mapping: x = bid&7 -> batch-x rows (L2-dirty there).
        const int x = bid & 7, g = bid >> 3;             // g in [0,96)
        const int nt = g % 12, mrow = g / 12;            // 12 nt x 8 mrow
        const int m0 = (x * 8 + mrow) * BM, n0 = nt * BN;

        const int lane = tid & 63;
        const int wid  = tid >> 6;
        const int wm = wid >> 1, wn = wid & 1;           // wave tile 32x32
        const int lnib = lane & 15, hi = lane >> 4;

        f32x4 acc[2][2] = {};

        auto stage = [&](int k0, int buf) {
            unsigned short* Asm = AsmB + buf * (BM * BK);
            unsigned short* Bsm = BsmB + buf * (BN * BK);
            #pragma unroll
            for (int it = 0; it < 2; ++it) {
                const int s   = it * 256 + tid;
                const int row = s >> 3, c8 = s & 7;
                const unsigned short* gp =
                    cat + (size_t)(m0 + row) * K + k0 + ((c8 ^ (row & 7)) << 3);
                __builtin_amdgcn_global_load_lds(AS1(gp), AS3(&Asm[s << 3]), 16, 0, 0);
            }
            #pragma unroll
            for (int it = 0; it < 2; ++it) {
                const int s   = it * 256 + tid;
                const int row = s >> 3, c8 = s & 7;
                const unsigned short* gp =
                    WT + (size_t)(n0 + row) * K + k0 + ((c8 ^ (row & 7)) << 3);
                __builtin_amdgcn_global_load_lds(AS1(gp), AS3(&Bsm[s << 3]), 16, 0, 0);
            }
        };

        auto compute = [&](int buf) {
            unsigned short* Asm = AsmB + buf * (BM * BK);
            unsigned short* Bsm = BsmB + buf * (BN * BK);
            #pragma unroll
            for (int kk = 0; kk < 2; ++kk) {
                short8 af[2], bf[2];
                const int cc = kk * 4 + hi;
                #pragma unroll
                for (int mf = 0; mf < 2; ++mf) {
                    const int r = wm * 32 + mf * 16 + lnib;
                    af[mf] = *(const short8*)&Asm[(r * 8 + (cc ^ (r & 7))) << 3];
                }
                #pragma unroll
                for (int nf = 0; nf < 2; ++nf) {
                    const int r = wn * 32 + nf * 16 + lnib;
                    bf[nf] = *(const short8*)&Bsm[(r * 8 + (cc ^ (r & 7))) << 3];
                }
                #pragma unroll
                for (int mf = 0; mf < 2; ++mf)
                    #pragma unroll
                    for (int nf = 0; nf < 2; ++nf)
                        acc[mf][nf] = __builtin_amdgcn_mfma_f32_16x16x32_bf16(
                            af[mf], bf[nf], acc[mf][nf], 0, 0, 0);
            }
        };

        constexpr int NT = K / BK;   // 24 K-steps

        __syncthreads();             // tbuf/LDS quiesce from phase A
        stage(0, 0);
        __syncthreads();

        int cur = 0;
        #pragma unroll 1
        for (int t = 0; t < NT - 1; ++t) {
            stage((t + 1) * BK, cur ^ 1);
            compute(cur);
            __syncthreads();
            cur ^= 1;
        }
        compute(cur);

        #pragma unroll
        for (int nf = 0; nf < 2; ++nf) {
            const int col = n0 + wn * 32 + nf * 16 + lnib;
            const float bv = bias[col];
            #pragma unroll
            for (int mf = 0; mf < 2; ++mf) {
                const int rbase = m0 + wm * 32 + mf * 16 + hi * 4;
                #pragma unroll
                for (int r = 0; r < 4; ++r)
                    out[(size_t)(rbase + r) * N + col] = acc[mf][nf][r] + bv;
            }
        }
    }
}

// ---------------------------------------------------------------------------
// FALLBACK path (r8 kernels) — used only if cooperative launch errors.
// ---------------------------------------------------------------------------
__global__ __launch_bounds__(256) void span_wt_kernel(
    const float* __restrict__ repr, const int* __restrict__ spans,
    const float* __restrict__ W, unsigned short* __restrict__ cat,
    unsigned short* __restrict__ WT)
{
    __shared__ float tbuf[32][33];
    const int bid = blockIdx.x;
    const int tid = threadIdx.x;

    if (bid < 1024) {
        const int wave = tid >> 6, lane = tid & 63;
        const int b = bid & 7;
        const int span = (b << 9) | (((bid >> 3) << 2) | wave);
        const bool is64 = ((spans[1] | spans[3] | spans[5] | spans[7]) == 0);
        int st, en;
        if (is64) { st = spans[4 * span];     en = spans[4 * span + 2]; }
        else      { st = spans[2 * span];     en = spans[2 * span + 1]; }
        const int cnt = en - st + 1;
        const float4* base = (const float4*)repr + (size_t)b * LL * (DD / 4);
        float4 mx[3], sm[3];
        #pragma unroll
        for (int c = 0; c < 3; ++c) {
            mx[c] = make_float4(-3.0e38f, -3.0e38f, -3.0e38f, -3.0e38f);
            sm[c] = make_float4(0.f, 0.f, 0.f, 0.f);
        }
        #define ACC(c, v)                                                      \
            mx[c].x = fmaxf(mx[c].x, (v).x); mx[c].y = fmaxf(mx[c].y, (v).y);  \
            mx[c].z = fmaxf(mx[c].z, (v).z); mx[c].w = fmaxf(mx[c].w, (v).w);  \
            sm[c].x += (v).x; sm[c].y += (v).y; sm[c].z += (v).z; sm[c].w += (v).w;
        int w = 0;
        if (cnt & 1) {
            const float4* rp = base + (size_t)en * (DD / 4) + lane;
            const float4 a0 = rp[0], a1 = rp[64], a2 = rp[128];
            ACC(0, a0); ACC(1, a1); ACC(2, a2);
            w = 1;
        }
        for (; w < cnt; w += 2) {
            const float4* r0 = base + (size_t)(en - w) * (DD / 4) + lane;
            const float4* r1 = r0 - (DD / 4);
            const float4 a0 = r0[0], a1 = r0[64], a2 = r0[128];
            const float4 b0 = r1[0], b1 = r1[64], b2 = r1[128];
            ACC(0, a0); ACC(1, a1); ACC(2, a2);
            ACC(0, b0); ACC(1, b1); ACC(2, b2);
        }
        #undef ACC
        const float inv = 1.0f / (float)cnt;
        unsigned short* crow = cat + (size_t)span * K;
        #pragma unroll
        for (int c = 0; c < 3; ++c) {
            const int d4 = c * 64 + lane;
            ushort4 omax, omean;
            omax.x  = f2bf(mx[c].x);       omax.y  = f2bf(mx[c].y);
            omax.z  = f2bf(mx[c].z);       omax.w  = f2bf(mx[c].w);
            omean.x = f2bf(sm[c].x * inv); omean.y = f2bf(sm[c].y * inv);
            omean.z = f2bf(sm[c].z * inv); omean.w = f2bf(sm[c].w * inv);
            *(ushort4*)(crow + d4 * 4)      = omax;
            *(ushort4*)(crow + DD + d4 * 4) = omean;
        }
    } else {
        const int tt = bid - 1024;
        const int n0 = (tt % 24) * 32, k0 = (tt / 24) * 32;
        const int tx = tid & 31, ty = tid >> 5;
        #pragma unroll
        for (int j = 0; j < 4; ++j)
            tbuf[ty + 8 * j][tx] = W[(size_t)(k0 + ty + 8 * j) * N + n0 + tx];
        __syncthreads();
        #pragma unroll
        for (int j = 0; j < 4; ++j)
            WT[(size_t)(n0 + ty + 8 * j) * K + k0 + tx] = f2bf(tbuf[tx][ty + 8 * j]);
    }
}

__global__ __launch_bounds__(256) void gemm_bias_kernel(
    const unsigned short* __restrict__ A, const unsigned short* __restrict__ WT,
    const float* __restrict__ bias, float* __restrict__ C)
{
    __shared__ unsigned short Asm[2][BM * BK];
    __shared__ unsigned short Bsm[2][BN * BK];

    const int tid = threadIdx.x;
    const int tile = (blockIdx.x & 7) * 96 + (blockIdx.x >> 3);
    const int mt = tile / 12, nt = tile % 12;
    const int m0 = mt * BM, n0 = nt * BN;
    const int lane = tid & 63;
    const int wid  = tid >> 6;
    const int wm = wid >> 1, wn = wid & 1;
    const int lnib = lane & 15, hi = lane >> 4;

    f32x4 acc[2][2] = {};

    auto stage = [&](int k0, int buf) {
        #pragma unroll
        for (int it = 0; it < 2; ++it) {
            const int s   = it * 256 + tid;
            const int row = s >> 3, c8 = s & 7;
            const unsigned short* g =
                A + (size_t)(m0 + row) * K + k0 + ((c8 ^ (row & 7)) << 3);
            __builtin_amdgcn_global_load_lds(AS1(g), AS3(&Asm[buf][s << 3]), 16, 0, 0);
        }
        #pragma unroll
        for (int it = 0; it < 2; ++it) {
            const int s   = it * 256 + tid;
            const int row = s >> 3, c8 = s & 7;
            const unsigned short* g =
                WT + (size_t)(n0 + row) * K + k0 + ((c8 ^ (row & 7)) << 3);
            __builtin_amdgcn_global_load_lds(AS1(g), AS3(&Bsm[buf][s << 3]), 16, 0, 0);
        }
    };
    auto compute = [&](int buf) {
        #pragma unroll
        for (int kk = 0; kk < 2; ++kk) {
            short8 af[2], bf[2];
            const int cc = kk * 4 + hi;
            #pragma unroll
            for (int mf = 0; mf < 2; ++mf) {
                const int r = wm * 32 + mf * 16 + lnib;
                af[mf] = *(const short8*)&Asm[buf][(r * 8 + (cc ^ (r & 7))) << 3];
            }
            #pragma unroll
            for (int nf = 0; nf < 2; ++nf) {
                const int r = wn * 32 + nf * 16 + lnib;
                bf[nf] = *(const short8*)&Bsm[buf][(r * 8 + (cc ^ (r & 7))) << 3];
            }
            #pragma unroll
            for (int mf = 0; mf < 2; ++mf)
                #pragma unroll
                for (int nf = 0; nf < 2; ++nf)
                    acc[mf][nf] = __builtin_amdgcn_mfma_f32_16x16x32_bf16(
                        af[mf], bf[nf], acc[mf][nf], 0, 0, 0);
        }
    };

    constexpr int NT = K / BK;
    stage(0, 0);
    __syncthreads();
    int cur = 0;
    #pragma unroll 1
    for (int t = 0; t < NT - 1; ++t) {
        stage((t + 1) * BK, cur ^ 1);
        compute(cur);
        __syncthreads();
        cur ^= 1;
    }
    compute(cur);

    #pragma unroll
    for (int nf = 0; nf < 2; ++nf) {
        const int col = n0 + wn * 32 + nf * 16 + lnib;
        const float bv = bias[col];
        #pragma unroll
        for (int mf = 0; mf < 2; ++mf) {
            const int rbase = m0 + wm * 32 + mf * 16 + hi * 4;
            #pragma unroll
            for (int r = 0; r < 4; ++r)
                C[(size_t)(rbase + r) * N + col] = acc[mf][nf][r] + bv;
        }
    }
}

// ---------------------------------------------------------------------------
extern "C" void kernel_launch(void* const* d_in, const int* in_sizes, int n_in,
                              void* d_out, int out_size, void* d_ws, size_t ws_size,
                              hipStream_t stream)
{
    const float* repr  = (const float*)d_in[0];  // (B,L,D) f32
    const int*   spans = (const int*)  d_in[1];  // (B,S,2)
    const float* Wd    = (const float*)d_in[2];  // (2D,D) f32
    const float* bias  = (const float*)d_in[3];  // (D)    f32
    float* out = (float*)d_out;                  // (M, N) f32

    unsigned short* catb  = (unsigned short*)d_ws;            // M*K   = 12.6 MB
    unsigned short* WT    = catb + (size_t)M * K;             // N*K   =  2.4 MB
    unsigned short* reprb = WT   + (size_t)N * K;             // B*L*D = 25.2 MB

    void* args[] = { (void*)&repr, (void*)&spans, (void*)&Wd, (void*)&bias,
                     (void*)&catb, (void*)&WT, (void*)&reprb, (void*)&out };
    const hipError_t err = hipLaunchCooperativeKernel(
        (const void*)fused_kernel, dim3(1024), dim3(256), args, 0, stream);

    if (err != hipSuccess) {
        // Deterministic fallback: r8 two-kernel path (f32 direct gather).
        span_wt_kernel<<<1024 + 1152, 256, 0, stream>>>(repr, spans, Wd, catb, WT);
        gemm_bias_kernel<<<768, 256, 0, stream>>>(catb, WT, bias, out);
    }
}

// Round 10
// 58.160 us; speedup vs baseline: 5.2397x; 5.2397x over previous
//
#include <hip/hip_runtime.h>
#include <cstdint>

// Problem constants
#define BB 8
#define LL 2048
#define DD 768
#define SS 512
#define MAXW 32

constexpr int M = BB * SS;   // 4096 spans
constexpr int K = 2 * DD;    // 1536
constexpr int N = DD;        // 768

typedef __attribute__((ext_vector_type(8))) short short8;   // 8 bf16 = 4 VGPRs
typedef __attribute__((ext_vector_type(4))) float f32x4;

__device__ __forceinline__ unsigned short f2bf(float f) {
    union { float f; unsigned int u; } v; v.f = f;
    unsigned int r = v.u + 0x7fffu + ((v.u >> 16) & 1u);  // RNE
    return (unsigned short)(r >> 16);
}

// generic -> addrspace casts for global_load_lds
#define AS1(p) reinterpret_cast<const __attribute__((address_space(1))) void*>( \
                   reinterpret_cast<uintptr_t>(p))
#define AS3(p) reinterpret_cast<__attribute__((address_space(3))) void*>( \
                   reinterpret_cast<uintptr_t>(p))

// ---------------------------------------------------------------------------
// Kernel 1: RANK-SORTED wave-per-span gather + W-transpose side blocks.
//  blocks [0, 512): 512 threads = 8 waves. Block computes its batch's
//    start-rank permutation in LDS (one rank/thread, 512 compares, ~0.6us,
//    deterministic tie-break by index), then wave w gathers the span of rank
//    (bid>>3)*8 + w. Sorted order => the ~4 spans re-reading any row run
//    within +-1 block on the SAME XCD (bid&7 = batch) => re-reads hit the
//    XCD L2 instead of the ~8 TB/s L3 path, and the cold HBM sweep is
//    sequential. f32 direct (no convert pass). Lane covers float4 chunks
//    {lane, lane+64, lane+128}; row loop x2 unrolled (6 loads in flight).
//  blocks [512, 512+1152): W_down (K x N f32) -> WT (N x K bf16).
// ---------------------------------------------------------------------------
__global__ __launch_bounds__(512) void span_wt_kernel(
    const float* __restrict__ repr,            // (B,L,D) f32
    const int*   __restrict__ spans,           // (B,S,2) int
    const float* __restrict__ W,               // (K,N) f32
    unsigned short* __restrict__ cat,          // (M, 2D) bf16
    unsigned short* __restrict__ WT)           // (N,K) bf16
{
    __shared__ int   s_start[512];
    __shared__ int   s_ord[512];
    __shared__ float tbuf[32][33];
    const int bid = blockIdx.x;
    const int tid = threadIdx.x;

    if (bid < 512) {
        const int b = bid & 7;                       // batch -> XCD pin (%8)

        // int64-layout sniff (values < 2048 so high words zero under int64)
        const bool is64 = ((spans[1] | spans[3] | spans[5] | spans[7]) == 0);
        const int stride = is64 ? 4 : 2;

        // ---- rank phase: load starts, compute permutation (1 span/thread)
        s_start[tid] = spans[(size_t)stride * ((b << 9) + tid)];
        __syncthreads();
        {
            const int sti = s_start[tid];
            int r = 0;
            #pragma unroll 8
            for (int j = 0; j < 512; ++j) {
                const int stj = s_start[j];          // LDS broadcast
                r += (int)((stj < sti) | ((stj == sti) & (j < tid)));
            }
            s_ord[r] = tid;                          // permutation: no conflict
        }
        __syncthreads();

        // ---- gather phase: wave w handles rank (bid>>3)*8 + w
        const int wave = tid >> 6, lane = tid & 63;
        const int sIdx = s_ord[(bid >> 3) * 8 + wave];   // wave-uniform
        const int span = (b << 9) | sIdx;

        int st, en;
        if (is64) { st = spans[4 * span];     en = spans[4 * span + 2]; }
        else      { st = spans[2 * span];     en = spans[2 * span + 1]; }
        const int cnt = en - st + 1;                 // 1..32, wave-uniform

        const float4* base = (const float4*)repr + (size_t)b * LL * (DD / 4);

        float4 mx[3], sm[3];
        #pragma unroll
        for (int c = 0; c < 3; ++c) {
            mx[c] = make_float4(-3.0e38f, -3.0e38f, -3.0e38f, -3.0e38f);
            sm[c] = make_float4(0.f, 0.f, 0.f, 0.f);
        }

        #define ACC(c, v)                                                      \
            mx[c].x = fmaxf(mx[c].x, (v).x); mx[c].y = fmaxf(mx[c].y, (v).y);  \
            mx[c].z = fmaxf(mx[c].z, (v).z); mx[c].w = fmaxf(mx[c].w, (v).w);  \
            sm[c].x += (v).x; sm[c].y += (v).y; sm[c].z += (v).z; sm[c].w += (v).w;

        int w = 0;
        if (cnt & 1) {                               // odd count: peel one row
            const float4* rp = base + (size_t)en * (DD / 4) + lane;
            const float4 a0 = rp[0], a1 = rp[64], a2 = rp[128];
            ACC(0, a0); ACC(1, a1); ACC(2, a2);
            w = 1;
        }
        for (; w < cnt; w += 2) {                    // 6 loads in flight
            const float4* r0 = base + (size_t)(en - w) * (DD / 4) + lane;
            const float4* r1 = r0 - (DD / 4);
            const float4 a0 = r0[0], a1 = r0[64], a2 = r0[128];
            const float4 b0 = r1[0], b1 = r1[64], b2 = r1[128];
            ACC(0, a0); ACC(1, a1); ACC(2, a2);
            ACC(0, b0); ACC(1, b1); ACC(2, b2);
        }
        #undef ACC

        const float inv = 1.0f / (float)cnt;
        unsigned short* crow = cat + (size_t)span * K;
        #pragma unroll
        for (int c = 0; c < 3; ++c) {
            const int d4 = c * 64 + lane;            // float4 index within row
            ushort4 omax, omean;
            omax.x  = f2bf(mx[c].x);       omax.y  = f2bf(mx[c].y);
            omax.z  = f2bf(mx[c].z);       omax.w  = f2bf(mx[c].w);
            omean.x = f2bf(sm[c].x * inv); omean.y = f2bf(sm[c].y * inv);
            omean.z = f2bf(sm[c].z * inv); omean.w = f2bf(sm[c].w * inv);
            *(ushort4*)(crow + d4 * 4)      = omax;
            *(ushort4*)(crow + DD + d4 * 4) = omean;
        }
    } else {
        // ---- W transpose+cast: 24 x 48 tiles of 32x32, 512 threads
        const int tt = bid - 512;
        const int n0 = (tt % 24) * 32, k0 = (tt / 24) * 32;
        const int tx = tid & 31, ty = tid >> 5;      // (32, 16)
        #pragma unroll
        for (int j = 0; j < 2; ++j)
            tbuf[ty + 16 * j][tx] = W[(size_t)(k0 + ty + 16 * j) * N + n0 + tx];
        __syncthreads();
        #pragma unroll
        for (int j = 0; j < 2; ++j)
            WT[(size_t)(n0 + ty + 16 * j) * K + k0 + tx] = f2bf(tbuf[tx][ty + 16 * j]);
    }
}

// ---------------------------------------------------------------------------
// Kernel 2: out = cat(bf16) @ WT(bf16)^T + bias, MFMA 16x16x32.
// BM=BN=BK=64; 256 threads = 4 waves (2x2); wave tile 32x32.
// Double-buffered prefetch-before-compute; grid 768 = 3 blocks/CU.
// XCD swizzle: 96 tiles/XCD -> A panel 1.57 MB + WT 2.4 MB ~ L2-resident.
// (UNCHANGED from rounds 7-8.)
// ---------------------------------------------------------------------------
constexpr int BM = 64, BN = 64, BK = 64;

__global__ __launch_bounds__(256) void gemm_bias_kernel(
    const unsigned short* __restrict__ A,    // (M, K)  bf16
    const unsigned short* __restrict__ WT,   // (N, K)  bf16
    const float* __restrict__ bias,          // (N)     f32
    float*       __restrict__ C)             // (M, N)  f32
{
    __shared__ unsigned short Asm[2][BM * BK];  // 2 x 8 KB, swizzled chunks
    __shared__ unsigned short Bsm[2][BN * BK];  // 2 x 8 KB

    const int tid = threadIdx.x;
    const int tile = (blockIdx.x & 7) * 96 + (blockIdx.x >> 3);
    const int mt = tile / 12, nt = tile % 12;
    const int m0 = mt * BM, n0 = nt * BN;

    const int lane = tid & 63;
    const int wid  = tid >> 6;
    const int wm = wid >> 1, wn = wid & 1;   // 2x2 wave grid, wave tile 32x32
    const int lnib = lane & 15, hi = lane >> 4;

    f32x4 acc[2][2] = {};

    auto stage = [&](int k0, int buf) {
        #pragma unroll
        for (int it = 0; it < 2; ++it) {
            const int s   = it * 256 + tid;
            const int row = s >> 3, c8 = s & 7;
            const unsigned short* g =
                A + (size_t)(m0 + row) * K + k0 + ((c8 ^ (row & 7)) << 3);
            __builtin_amdgcn_global_load_lds(AS1(g), AS3(&Asm[buf][s << 3]), 16, 0, 0);
        }
        #pragma unroll
        for (int it = 0; it < 2; ++it) {
            const int s   = it * 256 + tid;
            const int row = s >> 3, c8 = s & 7;
            const unsigned short* g =
                WT + (size_t)(n0 + row) * K + k0 + ((c8 ^ (row & 7)) << 3);
            __builtin_amdgcn_global_load_lds(AS1(g), AS3(&Bsm[buf][s << 3]), 16, 0, 0);
        }
    };

    auto compute = [&](int buf) {
        #pragma unroll
        for (int kk = 0; kk < 2; ++kk) {
            short8 af[2], bf[2];
            const int cc = kk * 4 + hi;
            #pragma unroll
            for (int mf = 0; mf < 2; ++mf) {
                const int r = wm * 32 + mf * 16 + lnib;
                af[mf] = *(const short8*)&Asm[buf][(r * 8 + (cc ^ (r & 7))) << 3];
            }
            #pragma unroll
            for (int nf = 0; nf < 2; ++nf) {
                const int r = wn * 32 + nf * 16 + lnib;
                bf[nf] = *(const short8*)&Bsm[buf][(r * 8 + (cc ^ (r & 7))) << 3];
            }
            #pragma unroll
            for (int mf = 0; mf < 2; ++mf)
                #pragma unroll
                for (int nf = 0; nf < 2; ++nf)
                    acc[mf][nf] = __builtin_amdgcn_mfma_f32_16x16x32_bf16(
                        af[mf], bf[nf], acc[mf][nf], 0, 0, 0);
        }
    };

    constexpr int NT = K / BK;   // 24 K-steps

    stage(0, 0);
    __syncthreads();             // vmcnt(0) drain: buf0 ready

    int cur = 0;
    #pragma unroll 1
    for (int t = 0; t < NT - 1; ++t) {
        stage((t + 1) * BK, cur ^ 1);  // issue next tile's loads first
        compute(cur);                   // MFMA on current while loads fly
        __syncthreads();                // next buf ready; cur free to reuse
        cur ^= 1;
    }
    compute(cur);

    // Epilogue: bias + store. C/D: col = lane&15, row = hi*4 + reg.
    #pragma unroll
    for (int nf = 0; nf < 2; ++nf) {
        const int col = n0 + wn * 32 + nf * 16 + lnib;
        const float bv = bias[col];
        #pragma unroll
        for (int mf = 0; mf < 2; ++mf) {
            const int rbase = m0 + wm * 32 + mf * 16 + hi * 4;
            #pragma unroll
            for (int r = 0; r < 4; ++r)
                C[(size_t)(rbase + r) * N + col] = acc[mf][nf][r] + bv;
        }
    }
}

// ---------------------------------------------------------------------------
extern "C" void kernel_launch(void* const* d_in, const int* in_sizes, int n_in,
                              void* d_out, int out_size, void* d_ws, size_t ws_size,
                              hipStream_t stream)
{
    const float* repr  = (const float*)d_in[0];  // (B,L,D) f32
    const int*   spans = (const int*)  d_in[1];  // (B,S,2)
    const float* Wd    = (const float*)d_in[2];  // (2D,D) f32
    const float* bias  = (const float*)d_in[3];  // (D)    f32
    float* out = (float*)d_out;                  // (M, N) f32

    unsigned short* catb = (unsigned short*)d_ws;             // M*K = 12.6 MB
    unsigned short* WT   = catb + (size_t)M * K;              // N*K =  2.4 MB

    span_wt_kernel<<<512 + 1152, 512, 0, stream>>>(repr, spans, Wd, catb, WT);
    gemm_bias_kernel<<<768, 256, 0, stream>>>(catb, WT, bias, out);
}

// Round 11
// 41.623 us; speedup vs baseline: 7.3214x; 1.3973x over previous
//
#include <hip/hip_runtime.h>
#include <cstdint>

// Problem constants
#define BB 8
#define LL 2048
#define DD 768
#define SS 512
#define MAXW 32

constexpr int M = BB * SS;   // 4096 spans
constexpr int K = 2 * DD;    // 1536
constexpr int N = DD;        // 768

typedef __attribute__((ext_vector_type(8))) short short8;   // 8 bf16 = 4 VGPRs
typedef __attribute__((ext_vector_type(4))) float f32x4;

__device__ __forceinline__ unsigned short f2bf(float f) {
    union { float f; unsigned int u; } v; v.f = f;
    unsigned int r = v.u + 0x7fffu + ((v.u >> 16) & 1u);  // RNE
    return (unsigned short)(r >> 16);
}

// generic -> addrspace casts for global_load_lds
#define AS1(p) reinterpret_cast<const __attribute__((address_space(1))) void*>( \
                   reinterpret_cast<uintptr_t>(p))
#define AS3(p) reinterpret_cast<__attribute__((address_space(3))) void*>( \
                   reinterpret_cast<uintptr_t>(p))

// ---------------------------------------------------------------------------
// Kernel 1 (fused span + W-transpose) — r7 structure, best measured (41.3us).
//  blocks [0, 4096): per-span masked max+mean reading repr f32 DIRECTLY.
//    192 threads, float4/lane, row loop unrolled x2 with dual accumulators.
//    Gather runs at ~8.2 TB/s logical = the CU load-path ceiling (measured:
//    bytes-proportional across f32/bf16 and cache residency — r6/r8/r10).
//  blocks [4096, 4096+1152): W_down (K x N f32) -> WT (N x K bf16).
// ---------------------------------------------------------------------------
__global__ __launch_bounds__(192) void span_wt_kernel(
    const float* __restrict__ repr,            // (B,L,D) f32
    const int*   __restrict__ spans,           // (B,S,2) int
    const float* __restrict__ W,               // (K,N) f32
    unsigned short* __restrict__ cat,          // (M, 2D) bf16
    unsigned short* __restrict__ WT)           // (N,K) bf16
{
    __shared__ float tbuf[32][33];
    const int bid = blockIdx.x;
    const int tid = threadIdx.x;

    if (bid < 4096) {
        const int b = bid & 7, s = bid >> 3;
        const int span = (b << 9) | s;
        const int t = tid;                     // 0..191, 4 dims (float4) each

        // int64-layout sniff (values < 2048 so high words zero under int64)
        const bool is64 = ((spans[1] | spans[3] | spans[5] | spans[7]) == 0);
        int st, en;
        if (is64) { st = spans[4 * span];     en = spans[4 * span + 2]; }
        else      { st = spans[2 * span];     en = spans[2 * span + 1]; }
        const int cnt = en - st + 1;           // 1..32, block-uniform

        const float4* base = (const float4*)repr + (size_t)b * LL * (DD / 4);

        float4 mx0 = make_float4(-3.0e38f, -3.0e38f, -3.0e38f, -3.0e38f);
        float4 mx1 = mx0;
        float4 sm0 = make_float4(0.f, 0.f, 0.f, 0.f);
        float4 sm1 = sm0;

        int w = 0;
        if (cnt & 1) {                          // odd count: peel one row
            const float4 v = base[(size_t)en * (DD / 4) + t];
            mx0.x = fmaxf(mx0.x, v.x);  mx0.y = fmaxf(mx0.y, v.y);
            mx0.z = fmaxf(mx0.z, v.z);  mx0.w = fmaxf(mx0.w, v.w);
            sm0.x += v.x;  sm0.y += v.y;  sm0.z += v.z;  sm0.w += v.w;
            w = 1;
        }
        for (; w < cnt; w += 2) {               // two independent load chains
            const float4 v0 = base[(size_t)(en - w)     * (DD / 4) + t];
            const float4 v1 = base[(size_t)(en - w - 1) * (DD / 4) + t];
            mx0.x = fmaxf(mx0.x, v0.x);  mx0.y = fmaxf(mx0.y, v0.y);
            mx0.z = fmaxf(mx0.z, v0.z);  mx0.w = fmaxf(mx0.w, v0.w);
            sm0.x += v0.x;  sm0.y += v0.y;  sm0.z += v0.z;  sm0.w += v0.w;
            mx1.x = fmaxf(mx1.x, v1.x);  mx1.y = fmaxf(mx1.y, v1.y);
            mx1.z = fmaxf(mx1.z, v1.z);  mx1.w = fmaxf(mx1.w, v1.w);
            sm1.x += v1.x;  sm1.y += v1.y;  sm1.z += v1.z;  sm1.w += v1.w;
        }
        const float4 mx = make_float4(fmaxf(mx0.x, mx1.x), fmaxf(mx0.y, mx1.y),
                                      fmaxf(mx0.z, mx1.z), fmaxf(mx0.w, mx1.w));
        const float4 sm = make_float4(sm0.x + sm1.x, sm0.y + sm1.y,
                                      sm0.z + sm1.z, sm0.w + sm1.w);

        const float inv = 1.0f / (float)cnt;
        unsigned short* crow = cat + (size_t)span * K;
        ushort4 omax, omean;
        omax.x  = f2bf(mx.x);       omax.y  = f2bf(mx.y);
        omax.z  = f2bf(mx.z);       omax.w  = f2bf(mx.w);
        omean.x = f2bf(sm.x * inv); omean.y = f2bf(sm.y * inv);
        omean.z = f2bf(sm.z * inv); omean.w = f2bf(sm.w * inv);
        *(ushort4*)(crow + t * 4)      = omax;
        *(ushort4*)(crow + DD + t * 4) = omean;
    } else {
        // ---- W transpose+cast: 24 x 48 tiles of 32x32, 192 threads
        const int tt = bid - 4096;
        const int n0 = (tt % 24) * 32, k0 = (tt / 24) * 32;
        const int tx = tid & 31, ty = tid >> 5;      // (32, 6)
        #pragma unroll
        for (int j = 0; j < 6; ++j) {
            const int row = ty + 6 * j;              // 0..35
            if (row < 32)
                tbuf[row][tx] = W[(size_t)(k0 + row) * N + n0 + tx];
        }
        __syncthreads();
        #pragma unroll
        for (int j = 0; j < 6; ++j) {
            const int row = ty + 6 * j;
            if (row < 32)
                WT[(size_t)(n0 + row) * K + k0 + tx] = f2bf(tbuf[tx][row]);
        }
    }
}

// ---------------------------------------------------------------------------
// Kernel 2: out = cat(bf16) @ WT(bf16)^T + bias, MFMA 16x16x32.
// BM=BN=BK=64; 256 threads = 4 waves (2x2); wave tile 32x32.
// Double-buffered prefetch-before-compute; grid 768 = 3 blocks/CU.
// XCD swizzle: 96 tiles/XCD -> A panel 1.57 MB + WT 2.4 MB ~ L2-resident.
// ---------------------------------------------------------------------------
constexpr int BM = 64, BN = 64, BK = 64;

__global__ __launch_bounds__(256) void gemm_bias_kernel(
    const unsigned short* __restrict__ A,    // (M, K)  bf16
    const unsigned short* __restrict__ WT,   // (N, K)  bf16
    const float* __restrict__ bias,          // (N)     f32
    float*       __restrict__ C)             // (M, N)  f32
{
    __shared__ unsigned short Asm[2][BM * BK];  // 2 x 8 KB, swizzled chunks
    __shared__ unsigned short Bsm[2][BN * BK];  // 2 x 8 KB

    const int tid = threadIdx.x;
    const int tile = (blockIdx.x & 7) * 96 + (blockIdx.x >> 3);
    const int mt = tile / 12, nt = tile % 12;
    const int m0 = mt * BM, n0 = nt * BN;

    const int lane = tid & 63;
    const int wid  = tid >> 6;
    const int wm = wid >> 1, wn = wid & 1;   // 2x2 wave grid, wave tile 32x32
    const int lnib = lane & 15, hi = lane >> 4;

    f32x4 acc[2][2] = {};

    auto stage = [&](int k0, int buf) {
        #pragma unroll
        for (int it = 0; it < 2; ++it) {
            const int s   = it * 256 + tid;
            const int row = s >> 3, c8 = s & 7;
            const unsigned short* g =
                A + (size_t)(m0 + row) * K + k0 + ((c8 ^ (row & 7)) << 3);
            __builtin_amdgcn_global_load_lds(AS1(g), AS3(&Asm[buf][s << 3]), 16, 0, 0);
        }
        #pragma unroll
        for (int it = 0; it < 2; ++it) {
            const int s   = it * 256 + tid;
            const int row = s >> 3, c8 = s & 7;
            const unsigned short* g =
                WT + (size_t)(n0 + row) * K + k0 + ((c8 ^ (row & 7)) << 3);
            __builtin_amdgcn_global_load_lds(AS1(g), AS3(&Bsm[buf][s << 3]), 16, 0, 0);
        }
    };

    auto compute = [&](int buf) {
        #pragma unroll
        for (int kk = 0; kk < 2; ++kk) {
            short8 af[2], bf[2];
            const int cc = kk * 4 + hi;
            #pragma unroll
            for (int mf = 0; mf < 2; ++mf) {
                const int r = wm * 32 + mf * 16 + lnib;
                af[mf] = *(const short8*)&Asm[buf][(r * 8 + (cc ^ (r & 7))) << 3];
            }
            #pragma unroll
            for (int nf = 0; nf < 2; ++nf) {
                const int r = wn * 32 + nf * 16 + lnib;
                bf[nf] = *(const short8*)&Bsm[buf][(r * 8 + (cc ^ (r & 7))) << 3];
            }
            #pragma unroll
            for (int mf = 0; mf < 2; ++mf)
                #pragma unroll
                for (int nf = 0; nf < 2; ++nf)
                    acc[mf][nf] = __builtin_amdgcn_mfma_f32_16x16x32_bf16(
                        af[mf], bf[nf], acc[mf][nf], 0, 0, 0);
        }
    };

    constexpr int NT = K / BK;   // 24 K-steps

    stage(0, 0);
    __syncthreads();             // vmcnt(0) drain: buf0 ready

    int cur = 0;
    #pragma unroll 1
    for (int t = 0; t < NT - 1; ++t) {
        stage((t + 1) * BK, cur ^ 1);  // issue next tile's loads first
        compute(cur);                   // MFMA on current while loads fly
        __syncthreads();                // next buf ready; cur free to reuse
        cur ^= 1;
    }
    compute(cur);

    // Epilogue: bias + store. C/D: col = lane&15, row = hi*4 + reg.
    #pragma unroll
    for (int nf = 0; nf < 2; ++nf) {
        const int col = n0 + wn * 32 + nf * 16 + lnib;
        const float bv = bias[col];
        #pragma unroll
        for (int mf = 0; mf < 2; ++mf) {
            const int rbase = m0 + wm * 32 + mf * 16 + hi * 4;
            #pragma unroll
            for (int r = 0; r < 4; ++r)
                C[(size_t)(rbase + r) * N + col] = acc[mf][nf][r] + bv;
        }
    }
}

// ---------------------------------------------------------------------------
extern "C" void kernel_launch(void* const* d_in, const int* in_sizes, int n_in,
                              void* d_out, int out_size, void* d_ws, size_t ws_size,
                              hipStream_t stream)
{
    const float* repr  = (const float*)d_in[0];  // (B,L,D) f32
    const int*   spans = (const int*)  d_in[1];  // (B,S,2)
    const float* Wd    = (const float*)d_in[2];  // (2D,D) f32
    const float* bias  = (const float*)d_in[3];  // (D)    f32
    float* out = (float*)d_out;                  // (M, N) f32

    unsigned short* catb = (unsigned short*)d_ws;             // M*K = 12.6 MB
    unsigned short* WT   = catb + (size_t)M * K;              // N*K =  2.4 MB

    span_wt_kernel<<<4096 + 1152, 192, 0, stream>>>(repr, spans, Wd, catb, WT);
    gemm_bias_kernel<<<768, 256, 0, stream>>>(catb, WT, bias, out);
}